// Round 5
// baseline (33057.993 us; speedup 1.0000x reference)
//
#include <hip/hip_runtime.h>
#include <math.h>

typedef unsigned short u16;
typedef __attribute__((ext_vector_type(8))) short s16x8;
typedef __attribute__((ext_vector_type(4))) short s16x4;
typedef __attribute__((ext_vector_type(4))) float f4v;

__device__ __forceinline__ float bf2f(short u) {
    union { unsigned int i; float f; } v;
    v.i = ((unsigned int)(u16)u) << 16;
    return v.f;
}
__device__ __forceinline__ u16 f2bf(float f) {
    union { float f; unsigned int i; } v; v.f = f;
    unsigned int x = v.i;
    return (u16)((x + 0x7FFFu + ((x >> 16) & 1u)) >> 16);
}

// ---------------- device-wide barrier (multi-wave safe) ----------------
__device__ __forceinline__ void grid_barrier(unsigned* bar, unsigned target) {
    __threadfence();       // each thread's global writes visible device-wide
    __syncthreads();       // all waves of this block done writing
    if (threadIdx.x == 0)
        __hip_atomic_fetch_add(bar, 1u, __ATOMIC_ACQ_REL, __HIP_MEMORY_SCOPE_AGENT);
    int spins = 0;
    while (__hip_atomic_load(bar, __ATOMIC_ACQUIRE, __HIP_MEMORY_SCOPE_AGENT) < target) {
        __builtin_amdgcn_s_sleep(2);
        if (++spins > (1 << 20)) break;    // bail-out against co-residency failure
    }
    __threadfence();       // acquire: invalidate L1 so fresh h is read
}

__global__ void zero_bar(unsigned* p, int n) {
    if ((int)threadIdx.x < n) p[threadIdx.x] = 0;
}

// ---------------- fp32 -> bf16 bulk conversion ----------------
__global__ __launch_bounds__(256)
void cvt_bf16v(const float* __restrict__ src, u16* __restrict__ dst, int n4) {
    int i = blockIdx.x * 256 + threadIdx.x;
    int stride = gridDim.x * 256;
    for (; i < n4; i += stride) {
        f4v v = ((const f4v*)src)[i];
        s16x4 o;
#pragma unroll
        for (int j = 0; j < 4; ++j) o[j] = (short)f2bf(v[j]);
        ((s16x4*)dst)[i] = o;
    }
}

// ---------------- layer0 input gates (one dir): xg = x @ W^T + bih, K=75 ----------------
__global__ __launch_bounds__(256)
void xg0_kernel(const float* __restrict__ x,   // [6400][75]
                const float* __restrict__ W,   // [3072][75] this dir
                const float* __restrict__ bih, // [3072]
                u16* __restrict__ xg)          // [6400][3072]
{
    const int bt0 = blockIdx.x * 16;
    __shared__ float xl[16][76];
    for (int idx = threadIdx.x; idx < 16 * 75; idx += 256) {
        int r = idx / 75, k = idx % 75;
        xl[r][k] = x[(size_t)(bt0 + r) * 75 + k];
    }
    __syncthreads();
    for (int i = 0; i < 12; ++i) {
        int g = threadIdx.x + i * 256;
        const float* wr = W + (size_t)g * 75;
        float bv = bih[g];
        float acc[16];
#pragma unroll
        for (int r = 0; r < 16; ++r) acc[r] = bv;
        for (int k = 0; k < 75; ++k) {
            float w = wr[k];
#pragma unroll
            for (int r = 0; r < 16; ++r) acc[r] += xl[r][k] * w;
        }
#pragma unroll
        for (int r = 0; r < 16; ++r)
            xg[(size_t)(bt0 + r) * 3072 + g] = f2bf(acc[r]);
    }
}

// ---------------- 128x128 MFMA GEMM: C[6400,3072] = A(bf16)[6400,2048] @ B(fp32)[3072,2048]^T + bias ----------------
__global__ __launch_bounds__(256)
void xg_gemm128(const u16* __restrict__ A, const float* __restrict__ Bm,
                const float* __restrict__ bias, u16* __restrict__ C)
{
    __shared__ u16 Al[128 * 40];
    __shared__ u16 Bl[128 * 40];
    const int m0 = blockIdx.x * 128;
    const int n0 = blockIdx.y * 128;
    const int wave = threadIdx.x >> 6, lane = threadIdx.x & 63;
    const int c = lane & 15, q = lane >> 4, kq = q * 8;
    const int sr = threadIdx.x >> 1;           // staging row 0..127
    const int sk = (threadIdx.x & 1) * 16;     // 0 or 16
    const int mbase = (wave & 1) * 64, nbase = (wave >> 1) * 64;
    f4v acc[4][4];
#pragma unroll
    for (int mt = 0; mt < 4; ++mt)
#pragma unroll
        for (int nt = 0; nt < 4; ++nt) acc[mt][nt] = (f4v){0.f, 0.f, 0.f, 0.f};

    for (int k0 = 0; k0 < 2048; k0 += 32) {
        const u16* ap = A + (size_t)(m0 + sr) * 2048 + k0 + sk;
        *(s16x8*)&Al[sr * 40 + sk]     = *(const s16x8*)ap;
        *(s16x8*)&Al[sr * 40 + sk + 8] = *(const s16x8*)(ap + 8);
        const float* bp = Bm + (size_t)(n0 + sr) * 2048 + k0 + sk;
        f4v v0 = *(const f4v*)bp, v1 = *(const f4v*)(bp + 4);
        f4v v2 = *(const f4v*)(bp + 8), v3 = *(const f4v*)(bp + 12);
        s16x8 b0, b1;
#pragma unroll
        for (int i = 0; i < 4; ++i) {
            b0[i] = (short)f2bf(v0[i]); b0[4 + i] = (short)f2bf(v1[i]);
            b1[i] = (short)f2bf(v2[i]); b1[4 + i] = (short)f2bf(v3[i]);
        }
        *(s16x8*)&Bl[sr * 40 + sk]     = b0;
        *(s16x8*)&Bl[sr * 40 + sk + 8] = b1;
        __syncthreads();
        s16x8 af[4], bf[4];
#pragma unroll
        for (int mt = 0; mt < 4; ++mt) af[mt] = *(const s16x8*)&Al[(mbase + mt * 16 + c) * 40 + kq];
#pragma unroll
        for (int nt = 0; nt < 4; ++nt) bf[nt] = *(const s16x8*)&Bl[(nbase + nt * 16 + c) * 40 + kq];
#pragma unroll
        for (int mt = 0; mt < 4; ++mt)
#pragma unroll
            for (int nt = 0; nt < 4; ++nt)
                acc[mt][nt] = __builtin_amdgcn_mfma_f32_16x16x32_bf16(af[mt], bf[nt], acc[mt][nt], 0, 0, 0);
        __syncthreads();
    }
#pragma unroll
    for (int nt = 0; nt < 4; ++nt) {
        int n = n0 + nbase + nt * 16 + c;
        float bb = bias[n];
#pragma unroll
        for (int mt = 0; mt < 4; ++mt) {
#pragma unroll
            for (int reg = 0; reg < 4; ++reg) {
                int m = m0 + mbase + mt * 16 + q * 4 + reg;
                C[(size_t)m * 3072 + n] = f2bf(acc[mt][nt][reg] + bb);
            }
        }
    }
}

// ---------------- persistent encoder layer (one dir): W in LDS, 4 waves ----------------
// 128 blocks x 256 thr. block = j-slice of 8 (24 gate rows). wave = m-tile of 16 batches.
__global__ __launch_bounds__(256)
void enc_persist2(const float* __restrict__ Whh,  // [3072][1024] this dir (fp32)
                  const float* __restrict__ bias, // [2][3072] this dir
                  const u16* __restrict__ xg,     // [6400][3072]
                  float* __restrict__ h32,        // [2][64][1024]
                  u16* __restrict__ hbf,          // [2][64][1024]
                  u16* __restrict__ y,            // [6400][2048]
                  int dir, unsigned* __restrict__ bar)
{
    __shared__ u16 wl[24][1032];       // rows: 0-7 r, 8-15 z, 16-23 n (49.5 KB)
    __shared__ float pre[4][16][8][3]; // [wave][m][jj][gate]
    const int tid = threadIdx.x;
    const int wave = tid >> 6, lane = tid & 63;
    const int j0 = blockIdx.x * 8;
    for (int idx = tid; idx < 3072; idx += 256) {     // 24 rows x 128 chunks of 8
        int row = idx >> 7, ck = idx & 127;
        int grow = (row >> 3) * 1024 + j0 + (row & 7);
        const float* src = Whh + (size_t)grow * 1024 + ck * 8;
        f4v v0 = *(const f4v*)src, v1 = *(const f4v*)(src + 4);
        s16x8 o;
#pragma unroll
        for (int i = 0; i < 4; ++i) { o[i] = (short)f2bf(v0[i]); o[4 + i] = (short)f2bf(v1[i]); }
        *(s16x8*)&wl[row][ck * 8] = o;
    }
    __syncthreads();
    const int c = lane & 15, q = lane >> 4, kq = q * 8;
    const int mrow = wave * 16 + c;

    for (int t = 0; t < 100; ++t) {
        f4v a1 = {0.f, 0.f, 0.f, 0.f}, a2 = a1;
        if (t > 0) {
            const u16* hb = hbf + (size_t)(t & 1) * 65536 + (size_t)mrow * 1024 + kq;
            for (int k0 = 0; k0 < 1024; k0 += 32) {
                s16x8 av = *(const s16x8*)(hb + k0);
                s16x8 b1 = *(const s16x8*)&wl[c][kq + k0];
                s16x8 b2 = *(const s16x8*)&wl[8 + c][kq + k0];
                a1 = __builtin_amdgcn_mfma_f32_16x16x32_bf16(av, b1, a1, 0, 0, 0);
                a2 = __builtin_amdgcn_mfma_f32_16x16x32_bf16(av, b2, a2, 0, 0, 0);
            }
        }
#pragma unroll
        for (int reg = 0; reg < 4; ++reg) {
            int m = q * 4 + reg;
            if (c < 8) pre[wave][m][c][0] = a1[reg];
            else { pre[wave][m][c - 8][1] = a1[reg]; pre[wave][m][c - 8][2] = a2[reg]; }
        }
        __syncthreads();
        for (int e = tid; e < 512; e += 256) {
            int b = e >> 3, jj = e & 7;
            int w2 = b >> 4, m2 = b & 15;
            float ar = pre[w2][m2][jj][0], az = pre[w2][m2][jj][1], an = pre[w2][m2][jj][2];
            int j = j0 + jj;
            const u16* xr = xg + ((size_t)b * 100 + t) * 3072;
            float prr = bf2f((short)xr[j]) + ar + bias[3072 + j];
            float pzz = bf2f((short)xr[1024 + j]) + az + bias[4096 + j];
            float pnn = bf2f((short)xr[2048 + j]);
            float hold = (t > 0) ? h32[(size_t)(t & 1) * 65536 + (size_t)b * 1024 + j] : 0.f;
            float rg = 1.f / (1.f + expf(-prr));
            float zg = 1.f / (1.f + expf(-pzz));
            float ng = tanhf(pnn + rg * (an + bias[5120 + j]));
            float hnew = (1.f - zg) * ng + zg * hold;
            int pp = (t + 1) & 1;
            h32[(size_t)pp * 65536 + (size_t)b * 1024 + j] = hnew;
            hbf[(size_t)pp * 65536 + (size_t)b * 1024 + j] = f2bf(hnew);
            y[((size_t)b * 100 + t) * 2048 + (size_t)dir * 1024 + j] = f2bf(hnew);
        }
        if (t < 99) grid_barrier(bar, 128u * (unsigned)(t + 1));
    }
}

// ---------------- persistent decoder: k-half1 LDS, k-half2 L2-private, 4 waves ----------------
// 256 blocks x 256 thr. block = j-slice of 8 (24 gate rows of [6144][2048]).
__global__ __launch_bounds__(256)
void dec_persist2(const u16* __restrict__ Wb,   // [6144][2048] bf16
                  const float* __restrict__ db, // [2][6144]
                  float* __restrict__ h32,      // [2][64][2048]
                  u16* __restrict__ hbf,        // [2][64][2048]
                  u16* __restrict__ ys,         // [6400][2048]
                  unsigned* __restrict__ bar)
{
    __shared__ u16 wl[24][1032];
    __shared__ float pre[4][16][8][3];
    const int tid = threadIdx.x;
    const int wave = tid >> 6, lane = tid & 63;
    const int j0 = blockIdx.x * 8;
    for (int idx = tid; idx < 3072; idx += 256) {
        int row = idx >> 7, ck = idx & 127;
        int grow = (row >> 3) * 2048 + j0 + (row & 7);
        *(s16x8*)&wl[row][ck * 8] = *(const s16x8*)(Wb + (size_t)grow * 2048 + ck * 8);
    }
    __syncthreads();
    const int c = lane & 15, q = lane >> 4, kq = q * 8;
    const int mrow = wave * 16 + c;
    const u16* wg1 = Wb + (size_t)((c >> 3) * 2048 + j0 + (c & 7)) * 2048 + kq;
    const u16* wg2 = Wb + (size_t)((((8 + c) >> 3)) * 2048 + j0 + (c & 7)) * 2048 + kq;

    for (int t = 0; t < 100; ++t) {
        f4v a1 = {0.f, 0.f, 0.f, 0.f}, a2 = a1;
        const u16* hb = hbf + (size_t)(t & 1) * 131072 + (size_t)mrow * 2048 + kq;
        for (int k0 = 0; k0 < 1024; k0 += 32) {
            s16x8 av = *(const s16x8*)(hb + k0);
            s16x8 b1 = *(const s16x8*)&wl[c][kq + k0];
            s16x8 b2 = *(const s16x8*)&wl[8 + c][kq + k0];
            a1 = __builtin_amdgcn_mfma_f32_16x16x32_bf16(av, b1, a1, 0, 0, 0);
            a2 = __builtin_amdgcn_mfma_f32_16x16x32_bf16(av, b2, a2, 0, 0, 0);
        }
        for (int k0 = 1024; k0 < 2048; k0 += 32) {
            s16x8 av = *(const s16x8*)(hb + k0);
            s16x8 b1 = *(const s16x8*)(wg1 + k0);
            s16x8 b2 = *(const s16x8*)(wg2 + k0);
            a1 = __builtin_amdgcn_mfma_f32_16x16x32_bf16(av, b1, a1, 0, 0, 0);
            a2 = __builtin_amdgcn_mfma_f32_16x16x32_bf16(av, b2, a2, 0, 0, 0);
        }
#pragma unroll
        for (int reg = 0; reg < 4; ++reg) {
            int m = q * 4 + reg;
            if (c < 8) pre[wave][m][c][0] = a1[reg];
            else { pre[wave][m][c - 8][1] = a1[reg]; pre[wave][m][c - 8][2] = a2[reg]; }
        }
        __syncthreads();
        for (int e = tid; e < 512; e += 256) {
            int b = e >> 3, jj = e & 7;
            int w2 = b >> 4, m2 = b & 15;
            float ar = pre[w2][m2][jj][0], az = pre[w2][m2][jj][1], an = pre[w2][m2][jj][2];
            int j = j0 + jj;
            float prr = db[j] + ar + db[6144 + j];
            float pzz = db[2048 + j] + az + db[8192 + j];
            float rg = 1.f / (1.f + expf(-prr));
            float zg = 1.f / (1.f + expf(-pzz));
            float ng = tanhf(db[4096 + j] + rg * (an + db[10240 + j]));
            float hold = h32[(size_t)(t & 1) * 131072 + (size_t)b * 2048 + j];
            float hnew = (1.f - zg) * ng + zg * hold;
            int pp = (t + 1) & 1;
            h32[(size_t)pp * 131072 + (size_t)b * 2048 + j] = hnew;
            hbf[(size_t)pp * 131072 + (size_t)b * 2048 + j] = f2bf(hnew);
            ys[((size_t)b * 100 + t) * 2048 + j] = f2bf(hnew);
        }
        if (t < 99) grid_barrier(bar, 256u * (unsigned)(t + 1));
    }
}

// ---------------- gather enc_hidden = y[b, sl-1]; init decoder h (pp0) ----------------
__global__ __launch_bounds__(256)
void gather_kernel(const int* __restrict__ seq_len, const u16* __restrict__ y,
                   float* __restrict__ out_enc, float* __restrict__ h32d,
                   u16* __restrict__ hbfd)
{
    int idx = blockIdx.x * 256 + threadIdx.x;   // < 131072
    int b = idx >> 11, j = idx & 2047;
    int s = seq_len[b];
    s = s < 1 ? 1 : (s > 100 ? 100 : s);
    u16 v = y[((size_t)b * 100 + (s - 1)) * 2048 + j];
    float f = bf2f((short)v);
    out_enc[idx] = f;
    h32d[idx] = f;
    hbfd[idx] = v;
}

// ---------------- output projection: dec_out[6400,75] = ys @ out_W^T + out_b ----------------
__global__ __launch_bounds__(256)
void proj_kernel(const u16* __restrict__ ys, const float* __restrict__ oW,
                 const float* __restrict__ oB, float* __restrict__ dec_out)
{
    const int r0 = blockIdx.x * 8;   // 800 blocks
    __shared__ float yl[8][2048];
    __shared__ float psum[3][8][76];
    for (int idx = threadIdx.x; idx < 2048; idx += 256) {
        int rr = idx >> 8, cc = idx & 255;
        s16x8 v = ((const s16x8*)(ys + (size_t)(r0 + rr) * 2048))[cc];
#pragma unroll
        for (int i = 0; i < 8; ++i) yl[rr][cc * 8 + i] = bf2f(v[i]);
    }
    __syncthreads();
    if (threadIdx.x < 225) {
        int d = threadIdx.x % 75, seg = threadIdx.x / 75;
        int ks = seg * 683, ke = ks + 683 < 2048 ? ks + 683 : 2048;
        const float* wr = oW + (size_t)d * 2048;
        float acc[8] = {0.f, 0.f, 0.f, 0.f, 0.f, 0.f, 0.f, 0.f};
        for (int k = ks; k < ke; ++k) {
            float w = wr[k];
#pragma unroll
            for (int r = 0; r < 8; ++r) acc[r] += yl[r][k] * w;
        }
#pragma unroll
        for (int r = 0; r < 8; ++r) psum[seg][r][d] = acc[r];
    }
    __syncthreads();
    for (int idx = threadIdx.x; idx < 600; idx += 256) {
        int r = idx / 75, d = idx % 75;
        dec_out[(size_t)(r0 + r) * 75 + d] =
            psum[0][r][d] + psum[1][r][d] + psum[2][r][d] + oB[d];
    }
}

// ============================ launcher ============================
extern "C" void kernel_launch(void* const* d_in, const int* in_sizes, int n_in,
                              void* d_out, int out_size, void* d_ws, size_t ws_size,
                              hipStream_t stream)
{
    const float* x    = (const float*)d_in[0];
    const int*   sl   = (const int*)d_in[1];
    const float* Wih0 = (const float*)d_in[2];
    const float* Whh0 = (const float*)d_in[3];
    const float* b0   = (const float*)d_in[4];
    const float* Wih  = (const float*)d_in[5];
    const float* Whh  = (const float*)d_in[6];
    const float* bE   = (const float*)d_in[7];
    const float* dWhh = (const float*)d_in[9];
    const float* dB   = (const float*)d_in[10];
    const float* oW   = (const float*)d_in[11];
    const float* oB   = (const float*)d_in[12];
    float* out_enc = (float*)d_out;            // [64][2048]
    float* dec_out = (float*)d_out + 131072;   // [64][100][75]

    char* ws = (char*)d_ws;
    const size_t XG_OFF   = 0;           // [6400][3072] bf16 = 39,321,600 (dec Wbf aliases)
    const size_t YA_OFF   = 39321600;    // [6400][2048] bf16
    const size_t YB_OFF   = 65536000;    // [6400][2048] bf16
    const size_t H32E_OFF = 91750400;    // [2][64][1024] f32
    const size_t HBFE_OFF = 92274688;    // [2][64][1024] bf16
    const size_t H32D_OFF = 92536832;    // [2][64][2048] f32
    const size_t HBFD_OFF = 93585408;    // [2][64][2048] bf16
    const size_t BAR_OFF  = 94109696;    // 64 counters

    u16*   xg   = (u16*)(ws + XG_OFF);
    u16*   y_a  = (u16*)(ws + YA_OFF);
    u16*   y_b  = (u16*)(ws + YB_OFF);
    float* h32E = (float*)(ws + H32E_OFF);
    u16*   hbfE = (u16*)(ws + HBFE_OFF);
    float* h32D = (float*)(ws + H32D_OFF);
    u16*   hbfD = (u16*)(ws + HBFD_OFF);
    unsigned* bar = (unsigned*)(ws + BAR_OFF);

    dim3 blk256(256);

    zero_bar<<<1, 64, 0, stream>>>(bar, 16);

    int slot = 0;
    for (int l = 0; l < 3; ++l) {
        const u16* y_in = (l == 1) ? y_a : y_b;      // l0 unused
        u16* y_out      = (l == 1) ? y_b : y_a;      // l0->y_a, l1->y_b, l2->y_a
        for (int d = 0; d < 2; ++d) {
            const float* Whh_src = (l == 0) ? (Whh0 + (size_t)d * 3145728)
                                            : (Whh + ((size_t)(l - 1) * 2 + d) * 3145728);
            const float* bias = (l == 0) ? (b0 + (size_t)d * 6144)
                                         : (bE + (size_t)(l - 1) * 12288 + (size_t)d * 6144);
            if (l == 0)
                xg0_kernel<<<dim3(400), blk256, 0, stream>>>(
                    x, Wih0 + (size_t)d * 230400, b0 + (size_t)d * 6144, xg);
            else
                xg_gemm128<<<dim3(50, 24), blk256, 0, stream>>>(
                    y_in, Wih + ((size_t)(l - 1) * 2 + d) * 6291456, bias, xg);
            enc_persist2<<<dim3(128), blk256, 0, stream>>>(
                Whh_src, bias, xg, h32E, hbfE, y_out, d, bar + slot);
            ++slot;
        }
    }
    gather_kernel<<<dim3(512), blk256, 0, stream>>>(sl, y_a, out_enc, h32D, hbfD);
    u16* dWbf = (u16*)(ws + XG_OFF);   // reuse xg region: [6144][2048] bf16 = 25.2 MB
    cvt_bf16v<<<dim3(2048), blk256, 0, stream>>>(dWhh, dWbf, 3145728);
    dec_persist2<<<dim3(256), blk256, 0, stream>>>(dWbf, dB, h32D, hbfD, y_b, bar + 6);
    proj_kernel<<<dim3(800), blk256, 0, stream>>>(y_b, oW, oB, dec_out);
}

// Round 6
// 28045.306 us; speedup vs baseline: 1.1787x; 1.1787x over previous
//
#include <hip/hip_runtime.h>
#include <math.h>

typedef unsigned short u16;
typedef __attribute__((ext_vector_type(8))) short s16x8;
typedef __attribute__((ext_vector_type(4))) short s16x4;
typedef __attribute__((ext_vector_type(4))) float f4v;

__device__ __forceinline__ float bf2f(short u) {
    union { unsigned int i; float f; } v;
    v.i = ((unsigned int)(u16)u) << 16;
    return v.f;
}
__device__ __forceinline__ u16 f2bf(float f) {
    union { float f; unsigned int i; } v; v.f = f;
    unsigned int x = v.i;
    return (u16)((x + 0x7FFFu + ((x >> 16) & 1u)) >> 16);
}

// ---------------- device-wide barrier: SINGLE spinner per block + backoff ----------------
__device__ __forceinline__ void grid_barrier(unsigned* bar, unsigned target) {
    __threadfence();       // release: this block's global writes visible device-wide
    __syncthreads();       // all waves of the block arrived (and their stores drained)
    if (threadIdx.x == 0) {
        __hip_atomic_fetch_add(bar, 1u, __ATOMIC_ACQ_REL, __HIP_MEMORY_SCOPE_AGENT);
        int spins = 0;
        while (__hip_atomic_load(bar, __ATOMIC_ACQUIRE, __HIP_MEMORY_SCOPE_AGENT) < target) {
            if (spins < 8)       __builtin_amdgcn_s_sleep(1);
            else if (spins < 32) __builtin_amdgcn_s_sleep(4);
            else                 __builtin_amdgcn_s_sleep(8);
            if (++spins > (1 << 20)) break;   // bail-out against co-residency failure
        }
    }
    __syncthreads();
    __threadfence();       // acquire side for all threads
}

__global__ void zero_bar(unsigned* p, int n) {
    if ((int)threadIdx.x < n) p[threadIdx.x] = 0;
}

// ---------------- fp32 -> bf16 bulk conversion ----------------
__global__ __launch_bounds__(256)
void cvt_bf16v(const float* __restrict__ src, u16* __restrict__ dst, int n4) {
    int i = blockIdx.x * 256 + threadIdx.x;
    int stride = gridDim.x * 256;
    for (; i < n4; i += stride) {
        f4v v = ((const f4v*)src)[i];
        s16x4 o;
#pragma unroll
        for (int j = 0; j < 4; ++j) o[j] = (short)f2bf(v[j]);
        ((s16x4*)dst)[i] = o;
    }
}

// ---------------- layer0 input gates (one dir): xg = x @ W^T + bih, K=75 ----------------
__global__ __launch_bounds__(256)
void xg0_kernel(const float* __restrict__ x,   // [6400][75]
                const float* __restrict__ W,   // [3072][75] this dir
                const float* __restrict__ bih, // [3072]
                u16* __restrict__ xg)          // [6400][3072]
{
    const int bt0 = blockIdx.x * 16;
    __shared__ float xl[16][76];
    for (int idx = threadIdx.x; idx < 16 * 75; idx += 256) {
        int r = idx / 75, k = idx % 75;
        xl[r][k] = x[(size_t)(bt0 + r) * 75 + k];
    }
    __syncthreads();
    for (int i = 0; i < 12; ++i) {
        int g = threadIdx.x + i * 256;
        const float* wr = W + (size_t)g * 75;
        float bv = bih[g];
        float acc[16];
#pragma unroll
        for (int r = 0; r < 16; ++r) acc[r] = bv;
        for (int k = 0; k < 75; ++k) {
            float w = wr[k];
#pragma unroll
            for (int r = 0; r < 16; ++r) acc[r] += xl[r][k] * w;
        }
#pragma unroll
        for (int r = 0; r < 16; ++r)
            xg[(size_t)(bt0 + r) * 3072 + g] = f2bf(acc[r]);
    }
}

// ---------------- 128x128 MFMA GEMM: C[6400,3072] = A(bf16)[6400,2048] @ B(fp32)[3072,2048]^T + bias ----------------
__global__ __launch_bounds__(256)
void xg_gemm128(const u16* __restrict__ A, const float* __restrict__ Bm,
                const float* __restrict__ bias, u16* __restrict__ C)
{
    __shared__ u16 Al[128 * 40];
    __shared__ u16 Bl[128 * 40];
    const int m0 = blockIdx.x * 128;
    const int n0 = blockIdx.y * 128;
    const int wave = threadIdx.x >> 6, lane = threadIdx.x & 63;
    const int c = lane & 15, q = lane >> 4, kq = q * 8;
    const int sr = threadIdx.x >> 1;
    const int sk = (threadIdx.x & 1) * 16;
    const int mbase = (wave & 1) * 64, nbase = (wave >> 1) * 64;
    f4v acc[4][4];
#pragma unroll
    for (int mt = 0; mt < 4; ++mt)
#pragma unroll
        for (int nt = 0; nt < 4; ++nt) acc[mt][nt] = (f4v){0.f, 0.f, 0.f, 0.f};

    for (int k0 = 0; k0 < 2048; k0 += 32) {
        const u16* ap = A + (size_t)(m0 + sr) * 2048 + k0 + sk;
        *(s16x8*)&Al[sr * 40 + sk]     = *(const s16x8*)ap;
        *(s16x8*)&Al[sr * 40 + sk + 8] = *(const s16x8*)(ap + 8);
        const float* bp = Bm + (size_t)(n0 + sr) * 2048 + k0 + sk;
        f4v v0 = *(const f4v*)bp, v1 = *(const f4v*)(bp + 4);
        f4v v2 = *(const f4v*)(bp + 8), v3 = *(const f4v*)(bp + 12);
        s16x8 b0, b1;
#pragma unroll
        for (int i = 0; i < 4; ++i) {
            b0[i] = (short)f2bf(v0[i]); b0[4 + i] = (short)f2bf(v1[i]);
            b1[i] = (short)f2bf(v2[i]); b1[4 + i] = (short)f2bf(v3[i]);
        }
        *(s16x8*)&Bl[sr * 40 + sk]     = b0;
        *(s16x8*)&Bl[sr * 40 + sk + 8] = b1;
        __syncthreads();
        s16x8 af[4], bf[4];
#pragma unroll
        for (int mt = 0; mt < 4; ++mt) af[mt] = *(const s16x8*)&Al[(mbase + mt * 16 + c) * 40 + kq];
#pragma unroll
        for (int nt = 0; nt < 4; ++nt) bf[nt] = *(const s16x8*)&Bl[(nbase + nt * 16 + c) * 40 + kq];
#pragma unroll
        for (int mt = 0; mt < 4; ++mt)
#pragma unroll
            for (int nt = 0; nt < 4; ++nt)
                acc[mt][nt] = __builtin_amdgcn_mfma_f32_16x16x32_bf16(af[mt], bf[nt], acc[mt][nt], 0, 0, 0);
        __syncthreads();
    }
#pragma unroll
    for (int nt = 0; nt < 4; ++nt) {
        int n = n0 + nbase + nt * 16 + c;
        float bb = bias[n];
#pragma unroll
        for (int mt = 0; mt < 4; ++mt) {
#pragma unroll
            for (int reg = 0; reg < 4; ++reg) {
                int m = m0 + mbase + mt * 16 + q * 4 + reg;
                C[(size_t)m * 3072 + n] = f2bf(acc[mt][nt][reg] + bb);
            }
        }
    }
}

// ---------------- persistent encoder layer (one dir): W in LDS, 4 waves ----------------
__global__ __launch_bounds__(256)
void enc_persist2(const float* __restrict__ Whh,  // [3072][1024] this dir (fp32)
                  const float* __restrict__ bias, // [2][3072] this dir
                  const u16* __restrict__ xg,     // [6400][3072]
                  float* __restrict__ h32,        // [2][64][1024]
                  u16* __restrict__ hbf,          // [2][64][1024]
                  u16* __restrict__ y,            // [6400][2048]
                  int dir, unsigned* __restrict__ bar)
{
    __shared__ u16 wl[24][1032];       // rows: 0-7 r, 8-15 z, 16-23 n
    __shared__ float pre[4][16][8][3]; // [wave][m][jj][gate]
    const int tid = threadIdx.x;
    const int wave = tid >> 6, lane = tid & 63;
    const int j0 = blockIdx.x * 8;
    for (int idx = tid; idx < 3072; idx += 256) {
        int row = idx >> 7, ck = idx & 127;
        int grow = (row >> 3) * 1024 + j0 + (row & 7);
        const float* src = Whh + (size_t)grow * 1024 + ck * 8;
        f4v v0 = *(const f4v*)src, v1 = *(const f4v*)(src + 4);
        s16x8 o;
#pragma unroll
        for (int i = 0; i < 4; ++i) { o[i] = (short)f2bf(v0[i]); o[4 + i] = (short)f2bf(v1[i]); }
        *(s16x8*)&wl[row][ck * 8] = o;
    }
    __syncthreads();
    const int c = lane & 15, q = lane >> 4, kq = q * 8;
    const int mrow = wave * 16 + c;

    for (int t = 0; t < 100; ++t) {
        f4v a1 = {0.f, 0.f, 0.f, 0.f}, a2 = a1;
        if (t > 0) {
            const u16* hb = hbf + (size_t)(t & 1) * 65536 + (size_t)mrow * 1024 + kq;
            for (int k0 = 0; k0 < 1024; k0 += 32) {
                s16x8 av = *(const s16x8*)(hb + k0);
                s16x8 b1 = *(const s16x8*)&wl[c][kq + k0];
                s16x8 b2 = *(const s16x8*)&wl[8 + c][kq + k0];
                a1 = __builtin_amdgcn_mfma_f32_16x16x32_bf16(av, b1, a1, 0, 0, 0);
                a2 = __builtin_amdgcn_mfma_f32_16x16x32_bf16(av, b2, a2, 0, 0, 0);
            }
        }
#pragma unroll
        for (int reg = 0; reg < 4; ++reg) {
            int m = q * 4 + reg;
            if (c < 8) pre[wave][m][c][0] = a1[reg];
            else { pre[wave][m][c - 8][1] = a1[reg]; pre[wave][m][c - 8][2] = a2[reg]; }
        }
        __syncthreads();
        for (int e = tid; e < 512; e += 256) {
            int b = e >> 3, jj = e & 7;
            int w2 = b >> 4, m2 = b & 15;
            float ar = pre[w2][m2][jj][0], az = pre[w2][m2][jj][1], an = pre[w2][m2][jj][2];
            int j = j0 + jj;
            const u16* xr = xg + ((size_t)b * 100 + t) * 3072;
            float prr = bf2f((short)xr[j]) + ar + bias[3072 + j];
            float pzz = bf2f((short)xr[1024 + j]) + az + bias[4096 + j];
            float pnn = bf2f((short)xr[2048 + j]);
            float hold = (t > 0) ? h32[(size_t)(t & 1) * 65536 + (size_t)b * 1024 + j] : 0.f;
            float rg = 1.f / (1.f + expf(-prr));
            float zg = 1.f / (1.f + expf(-pzz));
            float ng = tanhf(pnn + rg * (an + bias[5120 + j]));
            float hnew = (1.f - zg) * ng + zg * hold;
            int pp = (t + 1) & 1;
            h32[(size_t)pp * 65536 + (size_t)b * 1024 + j] = hnew;
            hbf[(size_t)pp * 65536 + (size_t)b * 1024 + j] = f2bf(hnew);
            y[((size_t)b * 100 + t) * 2048 + (size_t)dir * 1024 + j] = f2bf(hnew);
        }
        if (t < 99) grid_barrier(bar, 128u * (unsigned)(t + 1));
    }
}

// ---------------- persistent decoder: FULL W in LDS (98.7 KB), 4 waves ----------------
__global__ __launch_bounds__(256)
void dec_persist2(const u16* __restrict__ Wb,   // [6144][2048] bf16
                  const float* __restrict__ db, // [2][6144]
                  float* __restrict__ h32,      // [2][64][2048]
                  u16* __restrict__ hbf,        // [2][64][2048]
                  u16* __restrict__ ys,         // [6400][2048]
                  unsigned* __restrict__ bar)
{
    __shared__ u16 wl[24][2056];       // full K, rows 0-7 r / 8-15 z / 16-23 n
    __shared__ float pre[4][16][8][3];
    const int tid = threadIdx.x;
    const int wave = tid >> 6, lane = tid & 63;
    const int j0 = blockIdx.x * 8;
    for (int idx = tid; idx < 6144; idx += 256) {       // 24 rows x 256 chunks of 8
        int row = idx >> 8, ck = idx & 255;
        int grow = (row >> 3) * 2048 + j0 + (row & 7);
        *(s16x8*)&wl[row][ck * 8] = *(const s16x8*)(Wb + (size_t)grow * 2048 + ck * 8);
    }
    __syncthreads();
    const int c = lane & 15, q = lane >> 4, kq = q * 8;
    const int mrow = wave * 16 + c;

    for (int t = 0; t < 100; ++t) {
        f4v a1 = {0.f, 0.f, 0.f, 0.f}, a2 = a1;
        const u16* hb = hbf + (size_t)(t & 1) * 131072 + (size_t)mrow * 2048 + kq;
        for (int k0 = 0; k0 < 2048; k0 += 32) {
            s16x8 av = *(const s16x8*)(hb + k0);
            s16x8 b1 = *(const s16x8*)&wl[c][kq + k0];
            s16x8 b2 = *(const s16x8*)&wl[8 + c][kq + k0];
            a1 = __builtin_amdgcn_mfma_f32_16x16x32_bf16(av, b1, a1, 0, 0, 0);
            a2 = __builtin_amdgcn_mfma_f32_16x16x32_bf16(av, b2, a2, 0, 0, 0);
        }
#pragma unroll
        for (int reg = 0; reg < 4; ++reg) {
            int m = q * 4 + reg;
            if (c < 8) pre[wave][m][c][0] = a1[reg];
            else { pre[wave][m][c - 8][1] = a1[reg]; pre[wave][m][c - 8][2] = a2[reg]; }
        }
        __syncthreads();
        for (int e = tid; e < 512; e += 256) {
            int b = e >> 3, jj = e & 7;
            int w2 = b >> 4, m2 = b & 15;
            float ar = pre[w2][m2][jj][0], az = pre[w2][m2][jj][1], an = pre[w2][m2][jj][2];
            int j = j0 + jj;
            float prr = db[j] + ar + db[6144 + j];
            float pzz = db[2048 + j] + az + db[8192 + j];
            float rg = 1.f / (1.f + expf(-prr));
            float zg = 1.f / (1.f + expf(-pzz));
            float ng = tanhf(db[4096 + j] + rg * (an + db[10240 + j]));
            float hold = h32[(size_t)(t & 1) * 131072 + (size_t)b * 2048 + j];
            float hnew = (1.f - zg) * ng + zg * hold;
            int pp = (t + 1) & 1;
            h32[(size_t)pp * 131072 + (size_t)b * 2048 + j] = hnew;
            hbf[(size_t)pp * 131072 + (size_t)b * 2048 + j] = f2bf(hnew);
            ys[((size_t)b * 100 + t) * 2048 + j] = f2bf(hnew);
        }
        if (t < 99) grid_barrier(bar, 256u * (unsigned)(t + 1));
    }
}

// ---------------- gather enc_hidden = y[b, sl-1]; init decoder h (pp0) ----------------
__global__ __launch_bounds__(256)
void gather_kernel(const int* __restrict__ seq_len, const u16* __restrict__ y,
                   float* __restrict__ out_enc, float* __restrict__ h32d,
                   u16* __restrict__ hbfd)
{
    int idx = blockIdx.x * 256 + threadIdx.x;
    int b = idx >> 11, j = idx & 2047;
    int s = seq_len[b];
    s = s < 1 ? 1 : (s > 100 ? 100 : s);
    u16 v = y[((size_t)b * 100 + (s - 1)) * 2048 + j];
    float f = bf2f((short)v);
    out_enc[idx] = f;
    h32d[idx] = f;
    hbfd[idx] = v;
}

// ---------------- output projection ----------------
__global__ __launch_bounds__(256)
void proj_kernel(const u16* __restrict__ ys, const float* __restrict__ oW,
                 const float* __restrict__ oB, float* __restrict__ dec_out)
{
    const int r0 = blockIdx.x * 8;
    __shared__ float yl[8][2048];
    __shared__ float psum[3][8][76];
    for (int idx = threadIdx.x; idx < 2048; idx += 256) {
        int rr = idx >> 8, cc = idx & 255;
        s16x8 v = ((const s16x8*)(ys + (size_t)(r0 + rr) * 2048))[cc];
#pragma unroll
        for (int i = 0; i < 8; ++i) yl[rr][cc * 8 + i] = bf2f(v[i]);
    }
    __syncthreads();
    if (threadIdx.x < 225) {
        int d = threadIdx.x % 75, seg = threadIdx.x / 75;
        int ks = seg * 683, ke = ks + 683 < 2048 ? ks + 683 : 2048;
        const float* wr = oW + (size_t)d * 2048;
        float acc[8] = {0.f, 0.f, 0.f, 0.f, 0.f, 0.f, 0.f, 0.f};
        for (int k = ks; k < ke; ++k) {
            float w = wr[k];
#pragma unroll
            for (int r = 0; r < 8; ++r) acc[r] += yl[r][k] * w;
        }
#pragma unroll
        for (int r = 0; r < 8; ++r) psum[seg][r][d] = acc[r];
    }
    __syncthreads();
    for (int idx = threadIdx.x; idx < 600; idx += 256) {
        int r = idx / 75, d = idx % 75;
        dec_out[(size_t)(r0 + r) * 75 + d] =
            psum[0][r][d] + psum[1][r][d] + psum[2][r][d] + oB[d];
    }
}

// ============================ launcher ============================
extern "C" void kernel_launch(void* const* d_in, const int* in_sizes, int n_in,
                              void* d_out, int out_size, void* d_ws, size_t ws_size,
                              hipStream_t stream)
{
    const float* x    = (const float*)d_in[0];
    const int*   sl   = (const int*)d_in[1];
    const float* Wih0 = (const float*)d_in[2];
    const float* Whh0 = (const float*)d_in[3];
    const float* b0   = (const float*)d_in[4];
    const float* Wih  = (const float*)d_in[5];
    const float* Whh  = (const float*)d_in[6];
    const float* bE   = (const float*)d_in[7];
    const float* dWhh = (const float*)d_in[9];
    const float* dB   = (const float*)d_in[10];
    const float* oW   = (const float*)d_in[11];
    const float* oB   = (const float*)d_in[12];
    float* out_enc = (float*)d_out;            // [64][2048]
    float* dec_out = (float*)d_out + 131072;   // [64][100][75]

    char* ws = (char*)d_ws;
    const size_t XG_OFF   = 0;           // [6400][3072] bf16 = 39,321,600 (dec Wbf aliases)
    const size_t YA_OFF   = 39321600;    // [6400][2048] bf16
    const size_t YB_OFF   = 65536000;    // [6400][2048] bf16
    const size_t H32E_OFF = 91750400;    // [2][64][1024] f32
    const size_t HBFE_OFF = 92274688;    // [2][64][1024] bf16
    const size_t H32D_OFF = 92536832;    // [2][64][2048] f32
    const size_t HBFD_OFF = 93585408;    // [2][64][2048] bf16
    const size_t BAR_OFF  = 94109696;    // counters

    u16*   xg   = (u16*)(ws + XG_OFF);
    u16*   y_a  = (u16*)(ws + YA_OFF);
    u16*   y_b  = (u16*)(ws + YB_OFF);
    float* h32E = (float*)(ws + H32E_OFF);
    u16*   hbfE = (u16*)(ws + HBFE_OFF);
    float* h32D = (float*)(ws + H32D_OFF);
    u16*   hbfD = (u16*)(ws + HBFD_OFF);
    unsigned* bar = (unsigned*)(ws + BAR_OFF);

    dim3 blk256(256);

    zero_bar<<<1, 64, 0, stream>>>(bar, 16);

    int slot = 0;
    for (int l = 0; l < 3; ++l) {
        const u16* y_in = (l == 1) ? y_a : y_b;      // l0 unused
        u16* y_out      = (l == 1) ? y_b : y_a;      // l0->y_a, l1->y_b, l2->y_a
        for (int d = 0; d < 2; ++d) {
            const float* Whh_src = (l == 0) ? (Whh0 + (size_t)d * 3145728)
                                            : (Whh + ((size_t)(l - 1) * 2 + d) * 3145728);
            const float* bias = (l == 0) ? (b0 + (size_t)d * 6144)
                                         : (bE + (size_t)(l - 1) * 12288 + (size_t)d * 6144);
            if (l == 0)
                xg0_kernel<<<dim3(400), blk256, 0, stream>>>(
                    x, Wih0 + (size_t)d * 230400, b0 + (size_t)d * 6144, xg);
            else
                xg_gemm128<<<dim3(50, 24), blk256, 0, stream>>>(
                    y_in, Wih + ((size_t)(l - 1) * 2 + d) * 6291456, bias, xg);
            enc_persist2<<<dim3(128), blk256, 0, stream>>>(
                Whh_src, bias, xg, h32E, hbfE, y_out, d, bar + slot);
            ++slot;
        }
    }
    gather_kernel<<<dim3(512), blk256, 0, stream>>>(sl, y_a, out_enc, h32D, hbfD);
    u16* dWbf = (u16*)(ws + XG_OFF);   // reuse xg region: [6144][2048] bf16 = 25.2 MB
    cvt_bf16v<<<dim3(2048), blk256, 0, stream>>>(dWhh, dWbf, 3145728);
    dec_persist2<<<dim3(256), blk256, 0, stream>>>(dWbf, dB, h32D, hbfD, y_b, bar + 6);
    proj_kernel<<<dim3(800), blk256, 0, stream>>>(y_b, oW, oB, dec_out);
}